// Round 7
// baseline (2422.632 us; speedup 1.0000x reference)
//
#include <hip/hip_runtime.h>

// LSTM: L=2, B=32, T=256, N=M=1024, gates 4M=4096
// R7: R5 tile data path + strict lockstep, with WAVE-ROLE SPLIT.
// 128 blocks (64/layer, 16 m-cols each), 512 threads = 8 waves:
//   wave w: half = w&1 (0=x-input GEMM, 1=h GEMM), kw = w>>1 (K-slice of 256).
// Per iter: all waves co-stage h(t-1) -> bufH (8x16B/thread); x-waves run
// gemm(wx) on bufX (staged last tail) CONCURRENTLY with h-waves' gemm(wh);
// 8 partials reduce via gred (80KB aliased over bufH + 16KB of bufX; written
// after S2, read before S4, bufX rewritten only in tail after S4). Tail is
// stage-only (post-flag, overlaps flag propagation). Poll all 128 flags.

typedef __bf16 bf16x8 __attribute__((ext_vector_type(8)));
typedef float  f32x4  __attribute__((ext_vector_type(4)));
typedef unsigned u32x4 __attribute__((ext_vector_type(4)));

__device__ __forceinline__ unsigned short f2bf(float f) {
    union { float f; unsigned u; } v; v.f = f;
    unsigned u = v.u;
    unsigned r = u + 0x7fffu + ((u >> 16) & 1u);   // RNE
    return (unsigned short)(r >> 16);
}
__device__ __forceinline__ float sigmoidf_fast(float x) {
    return 1.0f / (1.0f + __expf(-x));
}
__device__ __forceinline__ float tanhf_fast(float x) {
    return 1.0f - 2.0f / (__expf(2.0f * x) + 1.0f);
}

// src: (L*4096, 1024) f32 -> dst: (L*4096, 2048) bf16 at column offset `off`
__global__ void cvt_w_concat(const float* __restrict__ src,
                             unsigned short* __restrict__ dst, int off, int n4) {
    int i = blockIdx.x * blockDim.x + threadIdx.x;
    int stride = gridDim.x * blockDim.x;
    for (; i < n4; i += stride) {
        float4 v = ((const float4*)src)[i];
        ushort4 o;
        o.x = f2bf(v.x); o.y = f2bf(v.y); o.z = f2bf(v.z); o.w = f2bf(v.w);
        int row = i >> 8;
        int c4  = i & 255;
        *(ushort4*)&dst[(size_t)row * 2048 + off + c4 * 4] = o;
    }
}

// x (B,T,N) f32 -> per-t tiles [t][blk 64][b 32][mi 16] bf16; one block per t
__global__ void cvt_x_tiles(const float* __restrict__ x,
                            unsigned short* __restrict__ xT) {
    int t = blockIdx.x, tid = threadIdx.x;
    unsigned short* tile = xT + (size_t)t * 32768;
    for (int b = 0; b < 32; ++b) {
        float4 v = *(const float4*)&x[((size_t)b * 256 + t) * 1024 + tid * 4];
        ushort4 o;
        o.x = f2bf(v.x); o.y = f2bf(v.y); o.z = f2bf(v.z); o.w = f2bf(v.w);
        *(ushort4*)&tile[(tid >> 2) * 512 + b * 16 + (tid & 3) * 4] = o;
    }
}

// h0 (L,B,M) f32 -> tiles [l][blk][b][mi] bf16; one block per l
__global__ void cvt_h0_tiles(const float* __restrict__ h0,
                             unsigned short* __restrict__ h0T) {
    int l = blockIdx.x, tid = threadIdx.x;
    unsigned short* tile = h0T + (size_t)l * 32768;
    for (int b = 0; b < 32; ++b) {
        float4 v = *(const float4*)&h0[((size_t)l * 32 + b) * 1024 + tid * 4];
        ushort4 o;
        o.x = f2bf(v.x); o.y = f2bf(v.y); o.z = f2bf(v.z); o.w = f2bf(v.w);
        *(ushort4*)&tile[(tid >> 2) * 512 + b * 16 + (tid & 3) * 4] = o;
    }
}

// outT [t][blk][b][mi] f32 -> out (B,T,M) f32; one block per t
__global__ void out_transpose(const float* __restrict__ outT,
                              float* __restrict__ out) {
    int t = blockIdx.x, tid = threadIdx.x;
    const float* tile = outT + (size_t)t * 32768;
    for (int b = 0; b < 32; ++b) {
        float4 v = *(const float4*)&tile[(tid >> 2) * 512 + b * 16 + (tid & 3) * 4];
        *(float4*)&out[((size_t)b * 256 + t) * 1024 + tid * 4] = v;
    }
}

__device__ __forceinline__ void pollge(const unsigned* fp, unsigned tgt) {
    while (true) {
        unsigned v = __hip_atomic_load(fp, __ATOMIC_RELAXED,
                                       __HIP_MEMORY_SCOPE_AGENT);
        if (__all((int)(v >= tgt))) break;
        __builtin_amdgcn_s_sleep(1);
    }
}

#define STAGE_LOADS8(ARR, PTR, FLAGS_STR) \
    _Pragma("unroll") \
    for (int si = 0; si < 8; si++) \
        asm volatile("global_load_dwordx4 %0, %1, off" FLAGS_STR \
                     : "=v"(ARR[si]) : "v"(PTR + si * 8192) : "memory");

__global__ __launch_bounds__(512, 2) void lstm_fused(
    const unsigned short* __restrict__ Wcat,  // (L,4096,2048) bf16 [Wih|Whh]
    const unsigned short* __restrict__ xT,    // 256 x 64KB tiles bf16
    unsigned short* __restrict__ seqT,        // 256 x 64KB tiles (layer0 h)
    const unsigned short* __restrict__ h0T,   // 2 x 64KB tiles
    unsigned short* __restrict__ hparT,       // 2 x 64KB tiles (layer1 parity)
    float* __restrict__ outT,                 // 256 x 128KB f32 tiles
    const float* __restrict__ c0,             // (L,32,1024) f32
    const float* __restrict__ bih, const float* __restrict__ bhh,
    float* __restrict__ out, unsigned int* flags)   // flags: [2][64] u32 packed
{
    __shared__ __align__(16) char pool[131072];              // bufH | bufX
    __shared__ __align__(16) unsigned short hout_bf[32][16]; // 1KB
    __shared__ __align__(16) float hout_f[32][16];           // 2KB

    const int tid  = threadIdx.x;
    const int lane = tid & 63;
    const int w    = tid >> 6;           // 0..7
    const int half = w & 1;              // 0 = x-role, 1 = h-role
    const int kw   = w >> 1;             // K-slice 0..3 (256 elems each)
    const int l    = blockIdx.x >> 6;
    const int bidl = blockIdx.x & 63;
    const int m0   = bidl * 16;
    const int n    = lane & 15;
    const int g    = lane >> 4;
    const int lk   = g * 8;
    const int nn7  = n & 7;

    char* const bH = pool;               // h tile (64KB)
    char* const bX = pool + 65536;       // x/seq tile (64KB)
    float* const gred = (float*)pool;    // [8][2][4][16][20] spans 81920B
#define GIDX(wv,bh,ct,nn,r) ((((((wv)*2+(bh))*4+(ct))*16+(nn))*20)+(r))

    // ---- persistent weights: this wave's half only (32 frags = 128 VGPR)
    bf16x8 wf[32];
    const unsigned short* Wl = Wcat + (size_t)l * 4096 * 2048;
    #pragma unroll
    for (int ct = 0; ct < 4; ct++) {
        int vc = ct * 16 + n;
        size_t jrow = (size_t)((vc & 3) * 1024 + m0 + (vc >> 2));
        #pragma unroll
        for (int kc = 0; kc < 8; kc++)
            wf[ct*8+kc] = *(const bf16x8*)
                &Wl[jrow*2048 + half*1024 + kw*256 + kc*32 + lk];
    }

    // ---- epilogue: thread -> (batch eb, single m = m0+sub)
    const int eb  = tid >> 4;            // 0..31
    const int sub = tid & 15;
    const int em  = m0 + sub;
    float bs[4];
    #pragma unroll
    for (int gg = 0; gg < 4; gg++)
        bs[gg] = bih[l*4096 + gg*1024 + em] + bhh[l*4096 + gg*1024 + em];
    float creg  = c0[(size_t)l * 32768 + eb * 1024 + em];
    float hlast = 0.f;
    const int uh = eb >> 4, urow = eb & 15;
    const int ctr = sub >> 2, nb = (sub & 3) * 4;

    // ---- staging: thread covers 16B chunks c = tid + si*512 of a 64KB tile
    // chunk c: blk = w + si*8, b = (tid>>1)&31, halfk = tid&1
    // LDS phys = b*2048 + ((blk*32 + halfk*16) ^ ((b&7)<<4)) = stOff + si*256
    const int sb = (tid >> 1) & 31;
    const int stOff = sb * 2048
                    + ((w * 32 + (tid & 1) * 16) ^ ((sb & 7) << 4));

    // ---- frag reads: phys = r*2048 + ((kw*512 + kc*64 + g*16) ^ ((r&7)<<4))
    const int hb64 = (nn7 >> 2) * 64;
    const int gx16 = (g ^ (nn7 & 3)) * 16;
    const int rOffA0 = n * 2048 + kw * 512 + gx16 + hb64;        // even kc
    const int rOffA1 = n * 2048 + kw * 512 + gx16 + (64 - hb64); // odd  kc

    f32x4 acc0[4], acc1[4];

    auto stage = [&](char* dst, const char* tb, bool byp) {
        u32x4 hv[8];
        const char* gp = tb + tid * 16;
        if (byp) { STAGE_LOADS8(hv, gp, " sc0 sc1") }
        else     { STAGE_LOADS8(hv, gp, "") }
        asm volatile("s_waitcnt vmcnt(0)" ::: "memory");
        #pragma unroll
        for (int si = 0; si < 8; si++)
            *(u32x4*)(dst + stOff + si * 256) = hv[si];
    };

    auto gemmbuf = [&](const char* base) {
        const char* pA0 = base + rOffA0;
        const char* pA1 = base + rOffA1;
        const char* pB0 = pA0 + 16 * 2048;
        const char* pB1 = pA1 + 16 * 2048;
        #pragma unroll
        for (int kc2 = 0; kc2 < 4; kc2++) {
            bf16x8 a0 = *(const bf16x8*)(pA0 + kc2 * 128);
            bf16x8 a1 = *(const bf16x8*)(pB0 + kc2 * 128);
            #pragma unroll
            for (int ct = 0; ct < 4; ct++) {
                acc0[ct] = __builtin_amdgcn_mfma_f32_16x16x32_bf16(a0, wf[ct*8+2*kc2], acc0[ct], 0,0,0);
                acc1[ct] = __builtin_amdgcn_mfma_f32_16x16x32_bf16(a1, wf[ct*8+2*kc2], acc1[ct], 0,0,0);
            }
            bf16x8 b0 = *(const bf16x8*)(pA1 + kc2 * 128);
            bf16x8 b1 = *(const bf16x8*)(pB1 + kc2 * 128);
            #pragma unroll
            for (int ct = 0; ct < 4; ct++) {
                acc0[ct] = __builtin_amdgcn_mfma_f32_16x16x32_bf16(b0, wf[ct*8+2*kc2+1], acc0[ct], 0,0,0);
                acc1[ct] = __builtin_amdgcn_mfma_f32_16x16x32_bf16(b1, wf[ct*8+2*kc2+1], acc1[ct], 0,0,0);
            }
        }
    };

    // ---- prologue: layer-0 preloads bufX with x(0)
    if (l == 0) stage(bX, (const char*)xT, false);
    __syncthreads();

    const int lag = l * 2;
    #pragma unroll 1
    for (int s = 0; s < 258; s++) {
        const int  t   = s - lag;
        const bool act = (t >= 0) && (t < 256);

        if (act) {
            // ---- co-stage h(t-1) into bufH (flag-confirmed <= iter s-1)
            const char* hb = (t == 0)
                ? (const char*)(h0T + (size_t)l * 32768)
                : (l == 0 ? (const char*)(seqT + (size_t)(t - 1) * 32768)
                          : (const char*)(hparT + (size_t)((t - 1) & 1) * 32768));
            stage(bH, hb, true);
            __syncthreads();                                  // S1

            // ---- role-split GEMMs: x-waves on bufX, h-waves on bufH
            #pragma unroll
            for (int ct = 0; ct < 4; ct++) {
                acc0[ct] = (f32x4){0.f, 0.f, 0.f, 0.f};
                acc1[ct] = (f32x4){0.f, 0.f, 0.f, 0.f};
            }
            gemmbuf(half ? bH : bX);
            __syncthreads();                                  // S2: gemms done

            // ---- 8 K-partials -> gred (aliases bufH + 16KB of bufX)
            {
                int r0 = g * 4;
                #pragma unroll
                for (int ct = 0; ct < 4; ct++) {
                    *(f32x4*)&gred[GIDX(w, 0, ct, n, r0)] = acc0[ct];
                    *(f32x4*)&gred[GIDX(w, 1, ct, n, r0)] = acc1[ct];
                }
            }
            __syncthreads();                                  // S3

            // ---- reduce 8 partials + cell update (1 cell per thread)
            float s0 = 0.f, s1 = 0.f, s2 = 0.f, s3 = 0.f;
            #pragma unroll
            for (int wv = 0; wv < 8; wv++) {
                s0 += gred[GIDX(wv, uh, ctr, nb + 0, urow)];
                s1 += gred[GIDX(wv, uh, ctr, nb + 1, urow)];
                s2 += gred[GIDX(wv, uh, ctr, nb + 2, urow)];
                s3 += gred[GIDX(wv, uh, ctr, nb + 3, urow)];
            }
            float gi = s0 + bs[0], gf = s1 + bs[1];
            float gg = s2 + bs[2], go = s3 + bs[3];
            float cn = sigmoidf_fast(gf) * creg + sigmoidf_fast(gi) * tanhf_fast(gg);
            float hn = sigmoidf_fast(go) * tanhf_fast(cn);
            creg = cn; hlast = hn;
            hout_bf[eb][sub] = f2bf(hn);
            if (l == 1) hout_f[eb][sub] = hn;
            __syncthreads();                                  // S4

            // ---- exchange store (wave 0) + drain + flag; outT (waves 1-2)
            if (tid < 64) {
                u32x4 v = *(const u32x4*)((const char*)&hout_bf[0][0] + tid * 16);
                const char* dp = (l == 0)
                    ? (const char*)(seqT  + (size_t)t * 32768)       + bidl * 1024 + tid * 16
                    : (const char*)(hparT + (size_t)(t & 1) * 32768) + bidl * 1024 + tid * 16;
                asm volatile("global_store_dwordx4 %0, %1, off sc0 sc1"
                             :: "v"(dp), "v"(v) : "memory");
                asm volatile("s_waitcnt vmcnt(0)" ::: "memory");
                if (tid == 0)
                    __hip_atomic_store(flags + l * 64 + bidl, (unsigned)(s + 1),
                                       __ATOMIC_RELAXED, __HIP_MEMORY_SCOPE_AGENT);
            } else if (l == 1 && tid < 192) {
                int u = tid - 64;
                f32x4 v = *(const f32x4*)((const char*)&hout_f[0][0] + u * 16);
                *(f32x4*)((char*)outT + (size_t)t * 131072 + bidl * 2048 + u * 16) = v;
            }
        } else if (tid == 0) {
            __hip_atomic_store(flags + l * 64 + bidl, (unsigned)(s + 1),
                               __ATOMIC_RELAXED, __HIP_MEMORY_SCOPE_AGENT);
        }

        // ---- tail: stage next input tile into bufX (post-flag, overlaps
        //      drain + flag propagation; reads data published <= iter s-1)
        const int  tn   = t + 1;
        const bool xact = (tn >= ((l == 0) ? 1 : 0)) && (tn <= 255);
        if (xact)
            stage(bX, l == 0 ? (const char*)(xT   + (size_t)tn * 32768)
                             : (const char*)(seqT + (size_t)tn * 32768), l == 1);

        // ---- strict global lockstep: all 128 flags >= s+1
        if (tid < 128) pollge(flags + tid, (unsigned)(s + 1));
        __syncthreads();                                      // S5
    }

    // ---- final states (1 float per thread)
    float* hF = out + (size_t)8192 * 1024 + (size_t)l * 32768;
    float* cF = out + (size_t)8192 * 1024 + 65536 + (size_t)l * 32768;
    hF[eb * 1024 + em] = hlast;
    cF[eb * 1024 + em] = creg;
}

extern "C" void kernel_launch(void* const* d_in, const int* in_sizes, int n_in,
                              void* d_out, int out_size, void* d_ws, size_t ws_size,
                              hipStream_t stream)
{
    const float* x   = (const float*)d_in[0];
    const float* h0  = (const float*)d_in[1];
    const float* c0  = (const float*)d_in[2];
    const float* Wih = (const float*)d_in[3];
    const float* Whh = (const float*)d_in[4];
    const float* bih = (const float*)d_in[5];
    const float* bhh = (const float*)d_in[6];
    float* out = (float*)d_out;

    char* p = (char*)d_ws;
    unsigned short* xT    = (unsigned short*)p; p += (size_t)256 * 32768 * 2;      // 16 MB
    unsigned short* seqT  = (unsigned short*)p; p += (size_t)256 * 32768 * 2;      // 16 MB
    unsigned short* Wcat  = (unsigned short*)p; p += (size_t)2 * 4096 * 2048 * 2;  // 32 MB
    unsigned short* h0T   = (unsigned short*)p; p += (size_t)2 * 32768 * 2;        // 128 KB
    unsigned short* hparT = (unsigned short*)p; p += (size_t)2 * 32768 * 2;        // 128 KB
    float*          outT  = (float*)p;          p += (size_t)256 * 32768 * 4;      // 32 MB
    unsigned int*   flags = (unsigned int*)p;   p += 4096;

    hipMemsetAsync(flags, 0, 4096, stream);
    cvt_w_concat<<<1024, 256, 0, stream>>>(Wih, Wcat, 0,    2 * 4096 * 256);
    cvt_w_concat<<<1024, 256, 0, stream>>>(Whh, Wcat, 1024, 2 * 4096 * 256);
    cvt_x_tiles<<<256, 256, 0, stream>>>(x, xT);
    cvt_h0_tiles<<<2, 256, 0, stream>>>(h0, h0T);

    lstm_fused<<<128, 512, 0, stream>>>(Wcat, xT, seqT, h0T, hparT, outT,
                                        c0, bih, bhh, out, flags);

    out_transpose<<<256, 256, 0, stream>>>(outT, out);
}

// Round 8
// 1320.940 us; speedup vs baseline: 1.8340x; 1.8340x over previous
//
#include <hip/hip_runtime.h>

// LSTM: L=2, B=32, T=256, N=M=1024, gates 4M=4096
// R8 = R5 (proven) + WAVE-LOCAL staging. Chunk remap blk=w*16+si makes wave w
// stage exactly its own GEMM K-window [w*256,+256) -> no cross-wave LDS deps
// -> S1/B5 barriers deleted (3 barriers/iter instead of 6). Counted vmcnt
// groups (12/8/4/0) interleave LDS-land + 2 k-steps of MFMA per group, so the
// stage tail overlaps compute and waves slip independently. Sync protocol,
// tile data path, reduce, epilogue, exchange, flags identical to R5.

typedef __bf16 bf16x8 __attribute__((ext_vector_type(8)));
typedef float  f32x4  __attribute__((ext_vector_type(4)));
typedef unsigned u32x4 __attribute__((ext_vector_type(4)));

__device__ __forceinline__ unsigned short f2bf(float f) {
    union { float f; unsigned u; } v; v.f = f;
    unsigned u = v.u;
    unsigned r = u + 0x7fffu + ((u >> 16) & 1u);   // RNE
    return (unsigned short)(r >> 16);
}
__device__ __forceinline__ float sigmoidf_fast(float x) {
    return 1.0f / (1.0f + __expf(-x));
}
__device__ __forceinline__ float tanhf_fast(float x) {
    return 1.0f - 2.0f / (__expf(2.0f * x) + 1.0f);
}

// src: (L*4096, 1024) f32 -> dst: (L*4096, 2048) bf16 at column offset `off`
__global__ void cvt_w_concat(const float* __restrict__ src,
                             unsigned short* __restrict__ dst, int off, int n4) {
    int i = blockIdx.x * blockDim.x + threadIdx.x;
    int stride = gridDim.x * blockDim.x;
    for (; i < n4; i += stride) {
        float4 v = ((const float4*)src)[i];
        ushort4 o;
        o.x = f2bf(v.x); o.y = f2bf(v.y); o.z = f2bf(v.z); o.w = f2bf(v.w);
        int row = i >> 8;
        int c4  = i & 255;
        *(ushort4*)&dst[(size_t)row * 2048 + off + c4 * 4] = o;
    }
}

// x (B,T,N) f32 -> per-t tiles [t][blk 64][b 32][mi 16] bf16; one block per t
__global__ void cvt_x_tiles(const float* __restrict__ x,
                            unsigned short* __restrict__ xT) {
    int t = blockIdx.x, tid = threadIdx.x;
    unsigned short* tile = xT + (size_t)t * 32768;
    for (int b = 0; b < 32; ++b) {
        float4 v = *(const float4*)&x[((size_t)b * 256 + t) * 1024 + tid * 4];
        ushort4 o;
        o.x = f2bf(v.x); o.y = f2bf(v.y); o.z = f2bf(v.z); o.w = f2bf(v.w);
        *(ushort4*)&tile[(tid >> 2) * 512 + b * 16 + (tid & 3) * 4] = o;
    }
}

// h0 (L,B,M) f32 -> tiles [l][blk][b][mi] bf16; one block per l
__global__ void cvt_h0_tiles(const float* __restrict__ h0,
                             unsigned short* __restrict__ h0T) {
    int l = blockIdx.x, tid = threadIdx.x;
    unsigned short* tile = h0T + (size_t)l * 32768;
    for (int b = 0; b < 32; ++b) {
        float4 v = *(const float4*)&h0[((size_t)l * 32 + b) * 1024 + tid * 4];
        ushort4 o;
        o.x = f2bf(v.x); o.y = f2bf(v.y); o.z = f2bf(v.z); o.w = f2bf(v.w);
        *(ushort4*)&tile[(tid >> 2) * 512 + b * 16 + (tid & 3) * 4] = o;
    }
}

// outT [t][blk][b][mi] f32 -> out (B,T,M) f32; one block per t
__global__ void out_transpose(const float* __restrict__ outT,
                              float* __restrict__ out) {
    int t = blockIdx.x, tid = threadIdx.x;
    const float* tile = outT + (size_t)t * 32768;
    for (int b = 0; b < 32; ++b) {
        float4 v = *(const float4*)&tile[(tid >> 2) * 512 + b * 16 + (tid & 3) * 4];
        *(float4*)&out[((size_t)b * 256 + t) * 1024 + tid * 4] = v;
    }
}

__device__ __forceinline__ void pollge(const unsigned* fp, unsigned tgt) {
    while (true) {
        unsigned v = __hip_atomic_load(fp, __ATOMIC_RELAXED,
                                       __HIP_MEMORY_SCOPE_AGENT);
        if (__all((int)(v >= tgt))) break;
        __builtin_amdgcn_s_sleep(1);
    }
}

__global__ __launch_bounds__(256, 1) void lstm_fused(
    const unsigned short* __restrict__ Wcat,  // (L,4096,2048) bf16 [Wih|Whh]
    const unsigned short* __restrict__ xT,    // 256 x 64KB tiles bf16
    unsigned short* __restrict__ seqT,        // 256 x 64KB tiles (layer0 h)
    const unsigned short* __restrict__ h0T,   // 2 x 64KB tiles
    unsigned short* __restrict__ hparT,       // 2 x 64KB tiles (layer1 parity)
    float* __restrict__ outT,                 // 256 x 128KB f32 tiles
    const float* __restrict__ c0,             // (L,32,1024) f32
    const float* __restrict__ bih, const float* __restrict__ bhh,
    float* __restrict__ out, unsigned int* flags)   // flags: [2][64] u32 packed
{
    __shared__ __align__(16) unsigned short buf[32][1024];   // 64KB swizzled
    __shared__ __align__(16) float gred[4][2][4][16][20];    // 40KB
    __shared__ __align__(16) unsigned short hout_bf[32][16]; // 1KB
    __shared__ __align__(16) float hout_f[32][16];           // 2KB

    const int tid  = threadIdx.x;
    const int lane = tid & 63;
    const int w    = tid >> 6;
    const int l    = blockIdx.x >> 6;
    const int bidl = blockIdx.x & 63;
    const int m0   = bidl * 16;
    const int n    = lane & 15;
    const int g    = lane >> 4;
    const int lk   = g * 8;
    const int nn7  = n & 7;

    // ---- persistent weights: wave w owns K-window [w*256,+256) in each half
    bf16x8 wx[32], wh[32];
    const unsigned short* Wl = Wcat + (size_t)l * 4096 * 2048;
    #pragma unroll
    for (int ct = 0; ct < 4; ct++) {
        int vc = ct * 16 + n;
        size_t jrow = (size_t)((vc & 3) * 1024 + m0 + (vc >> 2));
        #pragma unroll
        for (int kc = 0; kc < 8; kc++) {
            wx[ct*8+kc] = *(const bf16x8*)&Wl[jrow*2048 +        w*256 + kc*32 + lk];
            wh[ct*8+kc] = *(const bf16x8*)&Wl[jrow*2048 + 1024 + w*256 + kc*32 + lk];
        }
    }

    // ---- epilogue ownership: thread -> (batch eb, m-pair em,em+1)
    const int eb = lane >> 1;
    const int q  = lane & 1;
    const int em = m0 + 4 * w + 2 * q;
    float bs0[4], bs1[4];
    #pragma unroll
    for (int gg = 0; gg < 4; gg++) {
        bs0[gg] = bih[l*4096 + gg*1024 + em]     + bhh[l*4096 + gg*1024 + em];
        bs1[gg] = bih[l*4096 + gg*1024 + em + 1] + bhh[l*4096 + gg*1024 + em + 1];
    }
    float2 creg = *(const float2*)&c0[(size_t)l * 32768 + eb * 1024 + em];
    float2 hlast = {0.f, 0.f};
    const int uh = eb >> 4, urow = eb & 15;

    // ---- WAVE-LOCAL staging: lane -> (row sb, halfk); chunk si -> blk=w*16+si
    // source chunk: tile + (w*16+si)*1024 + sb*32 + halfk*16  (per-si: wave
    // reads one contiguous 1KB tile block -> coalesced)
    // LDS phys = sb*2048 + ((w*512 + si*32 + halfk*16) ^ ((sb&7)<<4))
    char* const bufb = (char*)&buf[0][0];
    const int sb     = lane >> 1;
    const int halfk  = lane & 1;
    const int srcOff = w * 16384 + sb * 32 + halfk * 16;
    const int sbRow  = sb * 2048;
    const int ldsCol = w * 512 + halfk * 16;
    const int swz    = (sb & 7) << 4;

    // ---- frag reads: phys = r*2048 + ((w*512+kc*64+g*16) ^ ((r&7)<<4))
    const int hb64 = (nn7 >> 2) * 64;
    const int gx16 = (g ^ (nn7 & 3)) * 16;
    const int rOffA0 = n * 2048 + w * 512 + gx16 + hb64;        // even kc
    const int rOffA1 = n * 2048 + w * 512 + gx16 + (64 - hb64); // odd  kc

    f32x4 acc0[4] = {}, acc1[4] = {};

    // fused wave-local stage + gemm: issue 16 loads, then 4 groups of
    // {vmcnt(N) -> land 4 chunks -> 2 k-steps of MFMA}. No barriers.
    auto stage_gemm = [&](const char* tb, const bf16x8* wfv, bool byp) {
        u32x4 hv[16];
        const char* gp = tb + srcOff;
        if (byp) {
            #pragma unroll
            for (int si = 0; si < 16; si++)
                asm volatile("global_load_dwordx4 %0, %1, off sc0 sc1"
                             : "=v"(hv[si]) : "v"(gp + si * 1024) : "memory");
        } else {
            #pragma unroll
            for (int si = 0; si < 16; si++)
                asm volatile("global_load_dwordx4 %0, %1, off"
                             : "=v"(hv[si]) : "v"(gp + si * 1024) : "memory");
        }
        const char* pA0 = bufb + rOffA0;
        const char* pA1 = bufb + rOffA1;
        const char* pB0 = pA0 + 16 * 2048;
        const char* pB1 = pA1 + 16 * 2048;
#define SGRP(G4, VM) \
        asm volatile("s_waitcnt vmcnt(" VM ")" ::: "memory"); \
        _Pragma("unroll") \
        for (int si = 4*(G4); si < 4*(G4)+4; si++) \
            *(u32x4*)(bufb + sbRow + ((ldsCol + si*32) ^ swz)) = hv[si]; \
        { \
            bf16x8 a0 = *(const bf16x8*)(pA0 + (G4)*128); \
            bf16x8 a1 = *(const bf16x8*)(pB0 + (G4)*128); \
            _Pragma("unroll") \
            for (int ct = 0; ct < 4; ct++) { \
                acc0[ct] = __builtin_amdgcn_mfma_f32_16x16x32_bf16(a0, wfv[ct*8+2*(G4)],   acc0[ct],0,0,0); \
                acc1[ct] = __builtin_amdgcn_mfma_f32_16x16x32_bf16(a1, wfv[ct*8+2*(G4)],   acc1[ct],0,0,0); \
            } \
            bf16x8 b0 = *(const bf16x8*)(pA1 + (G4)*128); \
            bf16x8 b1 = *(const bf16x8*)(pB1 + (G4)*128); \
            _Pragma("unroll") \
            for (int ct = 0; ct < 4; ct++) { \
                acc0[ct] = __builtin_amdgcn_mfma_f32_16x16x32_bf16(b0, wfv[ct*8+2*(G4)+1], acc0[ct],0,0,0); \
                acc1[ct] = __builtin_amdgcn_mfma_f32_16x16x32_bf16(b1, wfv[ct*8+2*(G4)+1], acc1[ct],0,0,0); \
            } \
        }
        SGRP(0, "12") SGRP(1, "8") SGRP(2, "4") SGRP(3, "0")
#undef SGRP
    };

    // ---- prologue: layer-0 computes x(0) partials (wave-local, no barrier)
    if (l == 0) stage_gemm((const char*)xT, wx, false);

    const int lag = l * 2;
    #pragma unroll 1
    for (int s = 0; s < 258; s++) {
        const int  t   = s - lag;
        const bool act = (t >= 0) && (t < 256);

        if (act) {
            // h(t-1): published <= iter s-1, drain-confirmed via flags+poll
            const char* hb = (t == 0)
                ? (const char*)(h0T + (size_t)l * 32768)
                : (l == 0 ? (const char*)(seqT + (size_t)(t - 1) * 32768)
                          : (const char*)(hparT + (size_t)((t - 1) & 1) * 32768));
            stage_gemm(hb, wh, true);     // acc += h-partials (x already in)

            // ---- K-partials -> gred (separate LDS region)
            {
                int r0 = g * 4;
                #pragma unroll
                for (int ct = 0; ct < 4; ct++) {
                    *(f32x4*)&gred[w][0][ct][n][r0] = acc0[ct];
                    *(f32x4*)&gred[w][1][ct][n][r0] = acc1[ct];
                }
            }
            __syncthreads();                                  // S3
            // reduce + cell update; thread's 8 gate cols: ct=w, n=8q+j
            float g8[8];
            #pragma unroll
            for (int j = 0; j < 8; j++) {
                g8[j] = (gred[0][uh][w][8*q+j][urow] + gred[1][uh][w][8*q+j][urow])
                      + (gred[2][uh][w][8*q+j][urow] + gred[3][uh][w][8*q+j][urow]);
            }
            float gi0 = g8[0] + bs0[0], gf0 = g8[1] + bs0[1];
            float gg0 = g8[2] + bs0[2], go0 = g8[3] + bs0[3];
            float gi1 = g8[4] + bs1[0], gf1 = g8[5] + bs1[1];
            float gg1 = g8[6] + bs1[2], go1 = g8[7] + bs1[3];

            float c0n = sigmoidf_fast(gf0) * creg.x + sigmoidf_fast(gi0) * tanhf_fast(gg0);
            float c1n = sigmoidf_fast(gf1) * creg.y + sigmoidf_fast(gi1) * tanhf_fast(gg1);
            float h0v = sigmoidf_fast(go0) * tanhf_fast(c0n);
            float h1v = sigmoidf_fast(go1) * tanhf_fast(c1n);
            creg.x = c0n; creg.y = c1n;
            hlast.x = h0v; hlast.y = h1v;

            unsigned hp = (unsigned)f2bf(h0v) | ((unsigned)f2bf(h1v) << 16);
            *(unsigned*)&hout_bf[eb][4*w + 2*q] = hp;
            if (l == 1) {
                float2 hv2 = {h0v, h1v};
                *(float2*)&hout_f[eb][4*w + 2*q] = hv2;
            }
            __syncthreads();                                  // S4
            // ---- coalesced exchange store + drain + flag (wave 0)
            if (tid < 64) {
                u32x4 v = *(const u32x4*)((const char*)&hout_bf[0][0] + tid * 16);
                const char* dp = (l == 0)
                    ? (const char*)(seqT  + (size_t)t * 32768)       + bidl * 1024 + tid * 16
                    : (const char*)(hparT + (size_t)(t & 1) * 32768) + bidl * 1024 + tid * 16;
                asm volatile("global_store_dwordx4 %0, %1, off sc0 sc1"
                             :: "v"(dp), "v"(v) : "memory");
                asm volatile("s_waitcnt vmcnt(0)" ::: "memory");
                if (tid == 0)
                    __hip_atomic_store(flags + l * 64 + bidl, (unsigned)(s + 1),
                                       __ATOMIC_RELAXED, __HIP_MEMORY_SCOPE_AGENT);
            } else if (l == 1 && tid < 192) {
                int u = tid - 64;
                f32x4 v = *(const f32x4*)((const char*)&hout_f[0][0] + u * 16);
                *(f32x4*)((char*)outT + (size_t)t * 131072 + bidl * 2048 + u * 16) = v;
            }
        } else if (tid == 0) {
            __hip_atomic_store(flags + l * 64 + bidl, (unsigned)(s + 1),
                               __ATOMIC_RELAXED, __HIP_MEMORY_SCOPE_AGENT);
        }

        // ---- tail: x/seq partials for t+1 (wave-local; reads data <= s-1)
        const int  tn   = t + 1;
        const bool xact = (tn >= ((l == 0) ? 1 : 0)) && (tn <= 255);
        if (xact) {
            #pragma unroll
            for (int ct = 0; ct < 4; ct++) {
                acc0[ct] = (f32x4){0.f, 0.f, 0.f, 0.f};
                acc1[ct] = (f32x4){0.f, 0.f, 0.f, 0.f};
            }
            stage_gemm(l == 0 ? (const char*)(xT   + (size_t)tn * 32768)
                              : (const char*)(seqT + (size_t)tn * 32768),
                       wx, l == 1);
        }

        // ---- strict global lockstep: all 128 flags >= s+1
        if (tid < 128) pollge(flags + tid, (unsigned)(s + 1));
        __syncthreads();                                      // S5
    }

    // ---- final states
    float* hF = out + (size_t)8192 * 1024 + (size_t)l * 32768;
    float* cF = out + (size_t)8192 * 1024 + 65536 + (size_t)l * 32768;
    float2 hf2 = {hlast.x, hlast.y};
    *(float2*)&hF[eb * 1024 + em] = hf2;
    float2 cf2 = {creg.x, creg.y};
    *(float2*)&cF[eb * 1024 + em] = cf2;
}

extern "C" void kernel_launch(void* const* d_in, const int* in_sizes, int n_in,
                              void* d_out, int out_size, void* d_ws, size_t ws_size,
                              hipStream_t stream)
{
    const float* x   = (const float*)d_in[0];
    const float* h0  = (const float*)d_in[1];
    const float* c0  = (const float*)d_in[2];
    const float* Wih = (const float*)d_in[3];
    const float* Whh = (const float*)d_in[4];
    const float* bih = (const float*)d_in[5];
    const float* bhh = (const float*)d_in[6];
    float* out = (float*)d_out;

    char* p = (char*)d_ws;
    unsigned short* xT    = (unsigned short*)p; p += (size_t)256 * 32768 * 2;      // 16 MB
    unsigned short* seqT  = (unsigned short*)p; p += (size_t)256 * 32768 * 2;      // 16 MB
    unsigned short* Wcat  = (unsigned short*)p; p += (size_t)2 * 4096 * 2048 * 2;  // 32 MB
    unsigned short* h0T   = (unsigned short*)p; p += (size_t)2 * 32768 * 2;        // 128 KB
    unsigned short* hparT = (unsigned short*)p; p += (size_t)2 * 32768 * 2;        // 128 KB
    float*          outT  = (float*)p;          p += (size_t)256 * 32768 * 4;      // 32 MB
    unsigned int*   flags = (unsigned int*)p;   p += 4096;

    hipMemsetAsync(flags, 0, 4096, stream);
    cvt_w_concat<<<1024, 256, 0, stream>>>(Wih, Wcat, 0,    2 * 4096 * 256);
    cvt_w_concat<<<1024, 256, 0, stream>>>(Whh, Wcat, 1024, 2 * 4096 * 256);
    cvt_x_tiles<<<256, 256, 0, stream>>>(x, xT);
    cvt_h0_tiles<<<2, 256, 0, stream>>>(h0, h0T);

    lstm_fused<<<128, 256, 0, stream>>>(Wcat, xT, seqT, h0T, hparT, outT,
                                        c0, bih, bhh, out, flags);

    out_transpose<<<256, 256, 0, stream>>>(outT, out);
}